// Round 2
// baseline (25441.592 us; speedup 1.0000x reference)
//
#include <hip/hip_runtime.h>
#include <hip/hip_bf16.h>

// LSTM: N=32, T=1024, D=H=512, bf16 dataset. Persistent cooperative kernel.
// R6 design: SINGLE-XCD serial loop.
//   Evidence: R3 (grid.sync), R4 (agent atomics), R5 (MALL flags, zero cache
//   maintenance) all land at 21-24 us/step with IDENTICAL counters -> the
//   floor is the physical cross-XCD round-trip cost (store-drain to MALL +
//   flag visibility + MALL h reload each ~us on the 8-chiplet fabric),
//   possibly amplified by DPM downclocking at ~2% utilization.
//   Fix: elect 32 worker WGs ON ONE XCD at runtime (HW_REG_XCC_ID, measured
//   m09 -- correctness never assumes the undefined blockIdx->XCD mapping).
//   Launch 256 WGs (1/CU co-resident => exactly 32 per XCD); per-XCD atomic
//   registration; first XCD to 32 wins. Workers run the same LSTM with
//   XCD-LOCAL sync: h stores are plain write-through-to-L2, release =
//   s_waitcnt vmcnt(0) (L2 = XCD coherence point), flags via sc0 (L1-bypass)
//   loads/stores in the winner's L2, acquire = L1-only buffer_inv. No sc1,
//   no MALL, no buffer_wbl2 anywhere in the serial loop.
//   The other 224 WGs run a duty-cycled FMA heater (covers the DPM/clock
//   hypothesis) polling a device-scope done flag.
// Compute structure unchanged vs R4/R5: WG w owns gate-cols [16w,16w+16) of
// all 4 gates, wave g = gate g; weights bf16-transposed in LDS; per step
// x-part MFMA before the wait, h-part after; gate exchange + fp32 c in LDS;
// h_t -> out[:,t,:]; step t+1 reads h from out[:,t,:].

#define NWG 32
#define TOTAL_WG 256
#define LDW 520              // 512 + 8 pad shorts (16B-aligned rows)
#define SMEM_BYTES (2*64*LDW*2 + 4*32*16*4 + 512*4)   // 143360 B

typedef __attribute__((ext_vector_type(8))) short s16x8;
typedef __attribute__((ext_vector_type(4))) float f32x4;
typedef __attribute__((ext_vector_type(4))) float f4v;

__device__ __forceinline__ float b2f(unsigned short u) {
  unsigned v = ((unsigned)u) << 16;
  return __builtin_bit_cast(float, v);
}
__device__ __forceinline__ unsigned short f2b(float f) {
  unsigned u = __builtin_bit_cast(unsigned, f);
  unsigned r = (u + 0x7fffu + ((u >> 16) & 1u)) >> 16;  // RNE
  return (unsigned short)r;
}
__device__ __forceinline__ float sigmoidf_(float x) {
  return 1.f / (1.f + __expf(-x));
}
__device__ __forceinline__ float tanhf_(float x) {
  float ax = fabsf(x);
  float e = __expf(-2.f * ax);          // in (0,1], no overflow
  float th = (1.f - e) / (1.f + e);
  return copysignf(th, x);
}

// ---- XCD-local (L2-scope) sync ops: sc0 bypasses L1 only ----
__device__ __forceinline__ void store_flag_l2(unsigned* p, unsigned v) {
  asm volatile("global_store_dword %0, %1, off sc0"
               :: "v"(p), "v"(v) : "memory");
}
__device__ __forceinline__ unsigned load_flag_l2(const unsigned* p) {
  unsigned r;
  asm volatile("global_load_dword %0, %1, off sc0\n\t"
               "s_waitcnt vmcnt(0)"
               : "=v"(r) : "v"(p) : "memory");
  return r;
}
// ---- device-scope (cross-XCD, MALL) ops: startup election + done flag ----
__device__ __forceinline__ void store_dword_dev(unsigned* p, unsigned v) {
  asm volatile("global_store_dword %0, %1, off sc0 sc1"
               :: "v"(p), "v"(v) : "memory");
}
__device__ __forceinline__ unsigned load_dword_dev(const unsigned* p) {
  unsigned r;
  asm volatile("global_load_dword %0, %1, off sc0 sc1\n\t"
               "s_waitcnt vmcnt(0)"
               : "=v"(r) : "v"(p) : "memory");
  return r;
}

// fp32[8] -> bf16 hi + lo fragments (kept for dtype-proofing; fp32 fallback)
__device__ __forceinline__ void split8(const float* p, s16x8& hi, s16x8& lo) {
  float tmp[8];
  *(f4v*)&tmp[0] = *(const f4v*)&p[0];
  *(f4v*)&tmp[4] = *(const f4v*)&p[4];
#pragma unroll
  for (int j = 0; j < 8; j++) {
    unsigned short h = f2b(tmp[j]);
    hi[j] = (short)h;
    lo[j] = (short)f2b(tmp[j] - b2f(h));
  }
}
__device__ __forceinline__ s16x8 cvt8(const float* p) {
  float tmp[8];
  *(f4v*)&tmp[0] = *(const f4v*)&p[0];
  *(f4v*)&tmp[4] = *(const f4v*)&p[4];
  s16x8 r;
#pragma unroll
  for (int j = 0; j < 8; j++) r[j] = (short)f2b(tmp[j]);
  return r;
}

// Uniform dtype sniff (one-time): bf16 normals vs fp32-as-halfwords.
__device__ __forceinline__ bool sniff_is_bf16(const unsigned short* wx) {
  int cnt = 0;
  for (int i = 0; i < 512; i++) {
    unsigned e = (wx[i] >> 7) & 0xFF;
    cnt += (e >= 0x60 && e <= 0x9F) ? 1 : 0;
  }
  return cnt >= 440;
}

template <bool F32>
__device__ __forceinline__ void lstm_body(
    const void* xv, const void* h0v, const void* Wxv, const void* Whv,
    const void* biasv, void* outv, unsigned* __restrict__ bar,
    unsigned char* smem, int w) {
  unsigned short* WhS = (unsigned short*)smem;                    // [64][LDW]
  unsigned short* WxS = (unsigned short*)(smem + 64 * LDW * 2);   // [64][LDW]
  float* gatebuf = (float*)(smem + 2 * 64 * LDW * 2);             // [4*32][16]
  float* cbuf = (float*)(smem + 2 * 64 * LDW * 2 + 4 * 32 * 16 * 4); // [512]

  const unsigned short* xb = (const unsigned short*)xv;
  const float* xf = (const float*)xv;
  const unsigned short* h0b = (const unsigned short*)h0v;
  const float* h0f = (const float*)h0v;

  const int tid = threadIdx.x;
  const int g = tid >> 6;          // wave = gate (i,f,o,g)
  const int lane = tid & 63;
  const int lm = lane & 15;
  const int q = lane >> 4;
  // w (logical worker id): owns cols w*16 .. w*16+15 of each gate

  // One-time staging of weight column slices -> LDS [col][k], bf16.
  for (int i = 0; i < 8; i++) {
    int id = tid + i * 256;        // 0..2047
    int gate = id & 3;
    int k = id >> 2;               // 0..511
    size_t base = (size_t)k * 2048 + gate * 512 + w * 16;
    if (F32) {
      const float* px = (const float*)Wxv + base;
      const float* ph = (const float*)Whv + base;
#pragma unroll
      for (int seg = 0; seg < 4; seg++) {
        f4v vx = *(const f4v*)(px + seg * 4);
        f4v vh = *(const f4v*)(ph + seg * 4);
#pragma unroll
        for (int j = 0; j < 4; j++) {
          WxS[(gate * 16 + seg * 4 + j) * LDW + k] = f2b(vx[j]);
          WhS[(gate * 16 + seg * 4 + j) * LDW + k] = f2b(vh[j]);
        }
      }
    } else {
      const unsigned short* px = (const unsigned short*)Wxv + base;
      const unsigned short* ph = (const unsigned short*)Whv + base;
      s16x8 vx0 = *(const s16x8*)&px[0];
      s16x8 vx1 = *(const s16x8*)&px[8];
      s16x8 vh0 = *(const s16x8*)&ph[0];
      s16x8 vh1 = *(const s16x8*)&ph[8];
#pragma unroll
      for (int j = 0; j < 8; j++) {
        WxS[(gate * 16 + j) * LDW + k]     = (unsigned short)vx0[j];
        WxS[(gate * 16 + 8 + j) * LDW + k] = (unsigned short)vx1[j];
        WhS[(gate * 16 + j) * LDW + k]     = (unsigned short)vh0[j];
        WhS[(gate * 16 + 8 + j) * LDW + k] = (unsigned short)vh1[j];
      }
    }
  }
  cbuf[tid] = 0.f;
  cbuf[tid + 256] = 0.f;

  float bv[2][4];
  for (int pp = 0; pp < 2; pp++) {
    int p = tid + pp * 256;
    int j = p & 15;
    for (int qq = 0; qq < 4; qq++) {
      int idx = qq * 512 + w * 16 + j;
      bv[pp][qq] = F32 ? ((const float*)biasv)[idx]
                       : b2f(((const unsigned short*)biasv)[idx]);
    }
  }
  __syncthreads();

  for (int t = 0; t < 1024; t++) {
    f32x4 acc0 = {0.f, 0.f, 0.f, 0.f};   // batch rows 0..15
    f32x4 acc1 = {0.f, 0.f, 0.f, 0.f};   // batch rows 16..31

    // ---- x-part (h-independent): issue BEFORE the barrier wait ----
    if (F32) {
      for (int kc = 0; kc < 16; kc++) {
        int k = kc * 32 + q * 8;
        s16x8 bfrag = *(const s16x8*)&WxS[(g * 16 + lm) * LDW + k];
        s16x8 a0 = cvt8(&xf[(size_t)(lm * 1024 + t) * 512 + k]);
        s16x8 a1 = cvt8(&xf[(size_t)((16 + lm) * 1024 + t) * 512 + k]);
        acc0 = __builtin_amdgcn_mfma_f32_16x16x32_bf16(a0, bfrag, acc0, 0, 0, 0);
        acc1 = __builtin_amdgcn_mfma_f32_16x16x32_bf16(a1, bfrag, acc1, 0, 0, 0);
      }
    } else {
      for (int kc = 0; kc < 16; kc++) {
        int k = kc * 32 + q * 8;
        s16x8 bfrag = *(const s16x8*)&WxS[(g * 16 + lm) * LDW + k];
        s16x8 a0 = *(const s16x8*)&xb[(size_t)(lm * 1024 + t) * 512 + k];
        s16x8 a1 = *(const s16x8*)&xb[(size_t)((16 + lm) * 1024 + t) * 512 + k];
        acc0 = __builtin_amdgcn_mfma_f32_16x16x32_bf16(a0, bfrag, acc0, 0, 0, 0);
        acc1 = __builtin_amdgcn_mfma_f32_16x16x32_bf16(a1, bfrag, acc1, 0, 0, 0);
      }
    }

    // ---- wait for h_{t-1} publication (XCD-local flags in winner's L2) ----
    if (t > 0) {
      if (tid < 64) {        // wave 0 polls; lane i reads flag[i&31]
        const unsigned target = (unsigned)t;
        const unsigned* fp = bar + (tid & 31);
        int guard = 0;
        for (;;) {
          unsigned v = load_flag_l2(fp);
          if (__all(v >= target)) break;
          if (++guard > (1 << 22)) break;   // anti-hang; never taken co-resident
        }
      }
      __syncthreads();
      // Acquire within the XCD: drop stale L1 lines only. Producer stores
      // already reached L2 (write-through + vmcnt(0) release). No sc1.
      asm volatile("buffer_inv" ::: "memory");
    }

    // ---- h-part ----
    if (F32) {
      float* outf = (float*)outv;
      const float* hpf = (t == 0) ? h0f : outf + (size_t)(t - 1) * 512;
      const size_t hstride = (t == 0) ? 512 : (size_t)1024 * 512;
      for (int kc = 0; kc < 16; kc++) {
        int k = kc * 32 + q * 8;
        s16x8 bfrag = *(const s16x8*)&WhS[(g * 16 + lm) * LDW + k];
        s16x8 hi0, lo0, hi1, lo1;
        split8(&hpf[lm * hstride + k], hi0, lo0);
        split8(&hpf[(16 + lm) * hstride + k], hi1, lo1);
        acc0 = __builtin_amdgcn_mfma_f32_16x16x32_bf16(hi0, bfrag, acc0, 0, 0, 0);
        acc0 = __builtin_amdgcn_mfma_f32_16x16x32_bf16(lo0, bfrag, acc0, 0, 0, 0);
        acc1 = __builtin_amdgcn_mfma_f32_16x16x32_bf16(hi1, bfrag, acc1, 0, 0, 0);
        acc1 = __builtin_amdgcn_mfma_f32_16x16x32_bf16(lo1, bfrag, acc1, 0, 0, 0);
      }
    } else {
      unsigned short* outb = (unsigned short*)outv;
      const unsigned short* hpb = (t == 0) ? h0b : outb + (size_t)(t - 1) * 512;
      const size_t hstride = (t == 0) ? 512 : (size_t)1024 * 512;
      for (int kc = 0; kc < 16; kc++) {
        int k = kc * 32 + q * 8;
        s16x8 bfrag = *(const s16x8*)&WhS[(g * 16 + lm) * LDW + k];
        s16x8 a0 = *(const s16x8*)&hpb[lm * hstride + k];
        s16x8 a1 = *(const s16x8*)&hpb[(16 + lm) * hstride + k];
        acc0 = __builtin_amdgcn_mfma_f32_16x16x32_bf16(a0, bfrag, acc0, 0, 0, 0);
        acc1 = __builtin_amdgcn_mfma_f32_16x16x32_bf16(a1, bfrag, acc1, 0, 0, 0);
      }
    }

    // C/D layout: col = lane&15 (j), row = q*4 + reg (batch row in 16-block)
    for (int r = 0; r < 4; r++) {
      gatebuf[(g * 32 + q * 4 + r) * 16 + lm] = acc0[r];
      gatebuf[(g * 32 + 16 + q * 4 + r) * 16 + lm] = acc1[r];
    }
    __syncthreads();

    for (int pp = 0; pp < 2; pp++) {
      int p = tid + pp * 256;
      int n = p >> 4, j = p & 15;
      float ai = gatebuf[(0 * 32 + n) * 16 + j] + bv[pp][0];
      float af = gatebuf[(1 * 32 + n) * 16 + j] + bv[pp][1];
      float ao = gatebuf[(2 * 32 + n) * 16 + j] + bv[pp][2];
      float ag = gatebuf[(3 * 32 + n) * 16 + j] + bv[pp][3];
      float iG = sigmoidf_(ai);
      float fG = sigmoidf_(af);
      float oG = sigmoidf_(ao);
      float gG = tanhf_(ag);
      float c = fG * cbuf[p] + iG * gG;
      cbuf[p] = c;
      float h = oG * tanhf_(c);
      size_t oidx = (size_t)(n * 1024 + t) * 512 + w * 16 + j;
      // Plain stores: write-through L1 -> winner XCD's L2 (coherence point).
      if (F32) ((float*)outv)[oidx] = h;
      else     ((unsigned short*)outv)[oidx] = f2b(h);
    }
    // Within-XCD release: drain own stores to L2, then all-threads barrier.
    asm volatile("s_waitcnt vmcnt(0)" ::: "memory");
    __syncthreads();

    if (t < 1023 && tid == 0) {
      store_flag_l2(bar + w, (unsigned)(t + 1));   // flag[w] = steps completed
    }
  }
}

__global__ __launch_bounds__(256) void lstm_kernel(
    const void* x, const void* h0, const void* Wx, const void* Wh,
    const void* bias, void* out, unsigned* ws) {
  extern __shared__ unsigned char smem[];
  __shared__ unsigned s_role[2];
  unsigned* flags  = ws;          // [0..31]  step flags (one 128B line)
  unsigned* cnt    = ws + 32;     // [32..47] per-XCD registration counters
  unsigned* winner = ws + 48;     // 0 = unset, else xcd+1
  unsigned* done   = ws + 49;     // heater stop flag

  // ---- runtime XCD election (correctness never assumes blockIdx->XCD) ----
  if (threadIdx.x == 0) {
    unsigned xcd;
    asm volatile("s_getreg_b32 %0, hwreg(HW_REG_XCC_ID)" : "=s"(xcd));
    xcd &= 0xFu;
    unsigned rank = atomicAdd(&cnt[xcd], 1u);      // device-scope RMW
    if (rank == 31u) atomicCAS(winner, 0u, xcd + 1u);
    // 256 co-resident WGs / 8 XCDs => some XCD reaches 32 (pigeonhole).
    unsigned wv; int guard = 0;
    do {
      wv = load_dword_dev(winner);
    } while (wv == 0u && ++guard < (1 << 26));
    s_role[0] = (wv == xcd + 1u && rank < 32u) ? 1u : 0u;
    s_role[1] = rank;
  }
  __syncthreads();

  if (s_role[0]) {
    int w = (int)s_role[1];
    if (sniff_is_bf16((const unsigned short*)Wx))
      lstm_body<false>(x, h0, Wx, Wh, bias, out, flags, smem, w);
    else
      lstm_body<true>(x, h0, Wx, Wh, bias, out, flags, smem, w);
    if (w == 0 && threadIdx.x == 0) store_dword_dev(done, 1u);
  } else {
    // Duty-cycled heater: keeps DPM from parking clocks while 32 workers
    // run a latency-bound loop. ~50% VALU busy, polls done every ~64 iters.
    float a = 1.0f;
    const float bm = 1.0000001f;
    for (int o = 0; o < (1 << 22); ++o) {
#pragma unroll
      for (int i = 0; i < 64; i++) a = __builtin_fmaf(a, bm, 1e-7f);
      __builtin_amdgcn_s_sleep(2);
      if ((o & 63) == 0) {
        if (load_dword_dev(done) != 0u) break;
      }
    }
    asm volatile("" :: "v"(a));   // keep heater work live (rule #17)
  }
}

extern "C" void kernel_launch(void* const* d_in, const int* in_sizes, int n_in,
                              void* d_out, int out_size, void* d_ws, size_t ws_size,
                              hipStream_t stream) {
  const void* x  = d_in[0];
  const void* h0 = d_in[1];
  const void* Wx = d_in[2];
  const void* Wh = d_in[3];
  const void* b  = d_in[4];
  void* out = d_out;
  unsigned* ws = (unsigned*)d_ws;   // poisoned 0xAA each call -> zero it

  hipMemsetAsync(ws, 0, 256, stream);   // flags + cnt + winner + done

  hipFuncSetAttribute((const void*)lstm_kernel,
                      hipFuncAttributeMaxDynamicSharedMemorySize, SMEM_BYTES);

  void* args[] = {(void*)&x, (void*)&h0, (void*)&Wx, (void*)&Wh,
                  (void*)&b, (void*)&out, (void*)&ws};
  hipLaunchCooperativeKernel((const void*)lstm_kernel, dim3(TOTAL_WG), dim3(256),
                             args, SMEM_BYTES, stream);
}

// Round 5
// 25163.428 us; speedup vs baseline: 1.0111x; 1.0111x over previous
//
#include <hip/hip_runtime.h>
#include <hip/hip_bf16.h>

// LSTM: N=32, T=1024, D=H=512, bf16 dataset. Persistent cooperative kernel.
// R9 = R6 (PASSED, 25.4 ms) + ONE lever: worker-CU heat during waits.
//   History: R6 passed (single-XCD election, L2 flags; FETCH 533->70 MB).
//   R7 (prefetch+burn+envelope) FAILED; R8 (prefetch ONLY) FAILED with the
//   same race signature -> the register-prefetch/launch_bounds(256,1) lever
//   is the poison (only shared diff); burn-in-wait is unindicted. Lever
//   retired.
//   Surviving theory for the mechanism-invariant ~21-25 us/step floor:
//   per-XCD DPM parks SCLK at ~2% utilization (cycle model says the step's
//   true path is ~4-10k cy; 21 us matches at ~500 MHz). R6's heaters heated
//   the WRONG XCDs (workers own all 32 CUs of the winner XCD). The heat must
//   come from the worker waves during their waits.
// THE ONE DIFF vs R6: the wait phase. Was: wave 0 polls flags, then
//   __syncthreads broadcast. Now: ALL FOUR waves poll the 32 flags
//   independently (sc0 L2 loads), burning dependent-FMA chains between
//   polls; each wave does its own buffer_inv when satisfied; the wait-phase
//   __syncthreads is removed (not needed: each wave independently proves
//   h_{t-1} is published; gatebuf/cbuf safety carried by the two retained
//   barriers B1 post-gatebuf / B2 post-epilogue, exactly as in R6).
//   During every wait all 4 SIMDs of every worker CU run ~full-rate FMA ->
//   CU busy ~2% -> 60-90% -> DPM sees activity.
// Everything else R6-VERBATIM: election, heaters on non-winner WGs, flag
// layout (ws[0..31], stride 1), memset 256, launch_bounds(256) (no
// min-waves), inline loads in MFMA loops (NO register prefetch).
// Compute structure: WG w owns gate-cols [16w,16w+16) of all 4 gates, wave
// g = gate g; weights bf16-transposed in LDS; gate exchange + fp32 c in LDS;
// h_t -> out[:,t,:]; step t+1 reads h from out[:,t,:].

#define NWG 32
#define TOTAL_WG 256
#define LDW 520              // 512 + 8 pad shorts (16B-aligned rows)
#define SMEM_BYTES (2*64*LDW*2 + 4*32*16*4 + 512*4)   // 143360 B

typedef __attribute__((ext_vector_type(8))) short s16x8;
typedef __attribute__((ext_vector_type(4))) float f32x4;
typedef __attribute__((ext_vector_type(4))) float f4v;

__device__ __forceinline__ float b2f(unsigned short u) {
  unsigned v = ((unsigned)u) << 16;
  return __builtin_bit_cast(float, v);
}
__device__ __forceinline__ unsigned short f2b(float f) {
  unsigned u = __builtin_bit_cast(unsigned, f);
  unsigned r = (u + 0x7fffu + ((u >> 16) & 1u)) >> 16;  // RNE
  return (unsigned short)r;
}
__device__ __forceinline__ float sigmoidf_(float x) {
  return 1.f / (1.f + __expf(-x));
}
__device__ __forceinline__ float tanhf_(float x) {
  float ax = fabsf(x);
  float e = __expf(-2.f * ax);          // in (0,1], no overflow
  float th = (1.f - e) / (1.f + e);
  return copysignf(th, x);
}

// Two interleaved dependent-FMA chains; ~500 cy per call. Keeps the SIMD's
// VALU issue slots busy during waits so per-XCD DPM sees activity.
__device__ __forceinline__ void burn(float& a, float& b) {
#pragma unroll
  for (int i = 0; i < 64; i++) {
    a = __builtin_fmaf(a, 1.0000002f, 1e-9f);
    b = __builtin_fmaf(b, 0.9999998f, 1e-9f);
  }
}

// ---- XCD-local (L2-scope) sync ops: sc0 bypasses L1 only ----
__device__ __forceinline__ void store_flag_l2(unsigned* p, unsigned v) {
  asm volatile("global_store_dword %0, %1, off sc0"
               :: "v"(p), "v"(v) : "memory");
}
__device__ __forceinline__ unsigned load_flag_l2(const unsigned* p) {
  unsigned r;
  asm volatile("global_load_dword %0, %1, off sc0\n\t"
               "s_waitcnt vmcnt(0)"
               : "=v"(r) : "v"(p) : "memory");
  return r;
}
// ---- device-scope (cross-XCD, MALL) ops: startup election + done flag ----
__device__ __forceinline__ void store_dword_dev(unsigned* p, unsigned v) {
  asm volatile("global_store_dword %0, %1, off sc0 sc1"
               :: "v"(p), "v"(v) : "memory");
}
__device__ __forceinline__ unsigned load_dword_dev(const unsigned* p) {
  unsigned r;
  asm volatile("global_load_dword %0, %1, off sc0 sc1\n\t"
               "s_waitcnt vmcnt(0)"
               : "=v"(r) : "v"(p) : "memory");
  return r;
}

// fp32[8] -> bf16 (fp32 fallback path only)
__device__ __forceinline__ void split8(const float* p, s16x8& hi, s16x8& lo) {
  float tmp[8];
  *(f4v*)&tmp[0] = *(const f4v*)&p[0];
  *(f4v*)&tmp[4] = *(const f4v*)&p[4];
#pragma unroll
  for (int j = 0; j < 8; j++) {
    unsigned short h = f2b(tmp[j]);
    hi[j] = (short)h;
    lo[j] = (short)f2b(tmp[j] - b2f(h));
  }
}
__device__ __forceinline__ s16x8 cvt8(const float* p) {
  float tmp[8];
  *(f4v*)&tmp[0] = *(const f4v*)&p[0];
  *(f4v*)&tmp[4] = *(const f4v*)&p[4];
  s16x8 r;
#pragma unroll
  for (int j = 0; j < 8; j++) r[j] = (short)f2b(tmp[j]);
  return r;
}

// Uniform dtype sniff (one-time): bf16 normals vs fp32-as-halfwords.
__device__ __forceinline__ bool sniff_is_bf16(const unsigned short* wx) {
  int cnt = 0;
  for (int i = 0; i < 512; i++) {
    unsigned e = (wx[i] >> 7) & 0xFF;
    cnt += (e >= 0x60 && e <= 0x9F) ? 1 : 0;
  }
  return cnt >= 440;
}

template <bool F32>
__device__ __forceinline__ void lstm_body(
    const void* xv, const void* h0v, const void* Wxv, const void* Whv,
    const void* biasv, void* outv, unsigned* __restrict__ bar,
    unsigned char* smem, int w) {
  unsigned short* WhS = (unsigned short*)smem;                    // [64][LDW]
  unsigned short* WxS = (unsigned short*)(smem + 64 * LDW * 2);   // [64][LDW]
  float* gatebuf = (float*)(smem + 2 * 64 * LDW * 2);             // [4*32][16]
  float* cbuf = (float*)(smem + 2 * 64 * LDW * 2 + 4 * 32 * 16 * 4); // [512]

  const unsigned short* xb = (const unsigned short*)xv;
  const float* xf = (const float*)xv;
  const unsigned short* h0b = (const unsigned short*)h0v;
  const float* h0f = (const float*)h0v;

  const int tid = threadIdx.x;
  const int g = tid >> 6;          // wave = gate (i,f,o,g)
  const int lane = tid & 63;
  const int lm = lane & 15;
  const int q = lane >> 4;
  // w (logical worker id): owns cols w*16 .. w*16+15 of each gate

  float bu0 = 1.0f, bu1 = 1.0f;    // burn accumulators (kept live at end)

  // One-time staging of weight column slices -> LDS [col][k], bf16.
  for (int i = 0; i < 8; i++) {
    int id = tid + i * 256;        // 0..2047
    int gate = id & 3;
    int k = id >> 2;               // 0..511
    size_t base = (size_t)k * 2048 + gate * 512 + w * 16;
    if (F32) {
      const float* px = (const float*)Wxv + base;
      const float* ph = (const float*)Whv + base;
#pragma unroll
      for (int seg = 0; seg < 4; seg++) {
        f4v vx = *(const f4v*)(px + seg * 4);
        f4v vh = *(const f4v*)(ph + seg * 4);
#pragma unroll
        for (int j = 0; j < 4; j++) {
          WxS[(gate * 16 + seg * 4 + j) * LDW + k] = f2b(vx[j]);
          WhS[(gate * 16 + seg * 4 + j) * LDW + k] = f2b(vh[j]);
        }
      }
    } else {
      const unsigned short* px = (const unsigned short*)Wxv + base;
      const unsigned short* ph = (const unsigned short*)Whv + base;
      s16x8 vx0 = *(const s16x8*)&px[0];
      s16x8 vx1 = *(const s16x8*)&px[8];
      s16x8 vh0 = *(const s16x8*)&ph[0];
      s16x8 vh1 = *(const s16x8*)&ph[8];
#pragma unroll
      for (int j = 0; j < 8; j++) {
        WxS[(gate * 16 + j) * LDW + k]     = (unsigned short)vx0[j];
        WxS[(gate * 16 + 8 + j) * LDW + k] = (unsigned short)vx1[j];
        WhS[(gate * 16 + j) * LDW + k]     = (unsigned short)vh0[j];
        WhS[(gate * 16 + 8 + j) * LDW + k] = (unsigned short)vh1[j];
      }
    }
  }
  cbuf[tid] = 0.f;
  cbuf[tid + 256] = 0.f;

  float bv[2][4];
  for (int pp = 0; pp < 2; pp++) {
    int p = tid + pp * 256;
    int j = p & 15;
    for (int qq = 0; qq < 4; qq++) {
      int idx = qq * 512 + w * 16 + j;
      bv[pp][qq] = F32 ? ((const float*)biasv)[idx]
                       : b2f(((const unsigned short*)biasv)[idx]);
    }
  }
  __syncthreads();

  for (int t = 0; t < 1024; t++) {
    f32x4 acc0 = {0.f, 0.f, 0.f, 0.f};   // batch rows 0..15
    f32x4 acc1 = {0.f, 0.f, 0.f, 0.f};   // batch rows 16..31

    // ---- x-part (h-independent): R6-verbatim inline loads ----
    if (F32) {
      for (int kc = 0; kc < 16; kc++) {
        int k = kc * 32 + q * 8;
        s16x8 bfrag = *(const s16x8*)&WxS[(g * 16 + lm) * LDW + k];
        s16x8 a0 = cvt8(&xf[(size_t)(lm * 1024 + t) * 512 + k]);
        s16x8 a1 = cvt8(&xf[(size_t)((16 + lm) * 1024 + t) * 512 + k]);
        acc0 = __builtin_amdgcn_mfma_f32_16x16x32_bf16(a0, bfrag, acc0, 0, 0, 0);
        acc1 = __builtin_amdgcn_mfma_f32_16x16x32_bf16(a1, bfrag, acc1, 0, 0, 0);
      }
    } else {
      for (int kc = 0; kc < 16; kc++) {
        int k = kc * 32 + q * 8;
        s16x8 bfrag = *(const s16x8*)&WxS[(g * 16 + lm) * LDW + k];
        s16x8 a0 = *(const s16x8*)&xb[(size_t)(lm * 1024 + t) * 512 + k];
        s16x8 a1 = *(const s16x8*)&xb[(size_t)((16 + lm) * 1024 + t) * 512 + k];
        acc0 = __builtin_amdgcn_mfma_f32_16x16x32_bf16(a0, bfrag, acc0, 0, 0, 0);
        acc1 = __builtin_amdgcn_mfma_f32_16x16x32_bf16(a1, bfrag, acc1, 0, 0, 0);
      }
    }

    // ---- THE R9 LEVER: wait for h_{t-1} with ALL FOUR waves polling
    // independently, FMA-burning between polls (worker-CU heat for DPM).
    // Each wave proves all 32 flags >= t itself, then L1-invalidates; the
    // old wave0-poll + __syncthreads broadcast is removed (gatebuf/cbuf
    // safety is carried by B1/B2 below, unchanged from R6).
    if (t > 0) {
      const unsigned target = (unsigned)t;
      const unsigned* fp = bar + (lane & 31);
      int guard = 0;
      for (;;) {
        unsigned v = load_flag_l2(fp);
        if (__all(v >= target)) break;
        burn(bu0, bu1);
        if (++guard > (1 << 22)) break;   // anti-hang; never taken co-resident
      }
      // Acquire within the XCD: drop stale L1 lines only. Producer stores
      // already reached L2 (write-through + vmcnt(0) release). No sc1.
      asm volatile("buffer_inv" ::: "memory");
    }

    // ---- h-part: R6-verbatim inline loads ----
    if (F32) {
      float* outf = (float*)outv;
      const float* hpf = (t == 0) ? h0f : outf + (size_t)(t - 1) * 512;
      const size_t hstride = (t == 0) ? 512 : (size_t)1024 * 512;
      for (int kc = 0; kc < 16; kc++) {
        int k = kc * 32 + q * 8;
        s16x8 bfrag = *(const s16x8*)&WhS[(g * 16 + lm) * LDW + k];
        s16x8 hi0, lo0, hi1, lo1;
        split8(&hpf[lm * hstride + k], hi0, lo0);
        split8(&hpf[(16 + lm) * hstride + k], hi1, lo1);
        acc0 = __builtin_amdgcn_mfma_f32_16x16x32_bf16(hi0, bfrag, acc0, 0, 0, 0);
        acc0 = __builtin_amdgcn_mfma_f32_16x16x32_bf16(lo0, bfrag, acc0, 0, 0, 0);
        acc1 = __builtin_amdgcn_mfma_f32_16x16x32_bf16(hi1, bfrag, acc1, 0, 0, 0);
        acc1 = __builtin_amdgcn_mfma_f32_16x16x32_bf16(lo1, bfrag, acc1, 0, 0, 0);
      }
    } else {
      unsigned short* outb = (unsigned short*)outv;
      const unsigned short* hpb = (t == 0) ? h0b : outb + (size_t)(t - 1) * 512;
      const size_t hstride = (t == 0) ? 512 : (size_t)1024 * 512;
      for (int kc = 0; kc < 16; kc++) {
        int k = kc * 32 + q * 8;
        s16x8 bfrag = *(const s16x8*)&WhS[(g * 16 + lm) * LDW + k];
        s16x8 a0 = *(const s16x8*)&hpb[lm * hstride + k];
        s16x8 a1 = *(const s16x8*)&hpb[(16 + lm) * hstride + k];
        acc0 = __builtin_amdgcn_mfma_f32_16x16x32_bf16(a0, bfrag, acc0, 0, 0, 0);
        acc1 = __builtin_amdgcn_mfma_f32_16x16x32_bf16(a1, bfrag, acc1, 0, 0, 0);
      }
    }

    // C/D layout: col = lane&15 (j), row = q*4 + reg (batch row in 16-block)
    for (int r = 0; r < 4; r++) {
      gatebuf[(g * 32 + q * 4 + r) * 16 + lm] = acc0[r];
      gatebuf[(g * 32 + 16 + q * 4 + r) * 16 + lm] = acc1[r];
    }
    __syncthreads();   // B1: gatebuf@t written before cross-wave reads

    for (int pp = 0; pp < 2; pp++) {
      int p = tid + pp * 256;
      int n = p >> 4, j = p & 15;
      float ai = gatebuf[(0 * 32 + n) * 16 + j] + bv[pp][0];
      float af = gatebuf[(1 * 32 + n) * 16 + j] + bv[pp][1];
      float ao = gatebuf[(2 * 32 + n) * 16 + j] + bv[pp][2];
      float ag = gatebuf[(3 * 32 + n) * 16 + j] + bv[pp][3];
      float iG = sigmoidf_(ai);
      float fG = sigmoidf_(af);
      float oG = sigmoidf_(ao);
      float gG = tanhf_(ag);
      float c = fG * cbuf[p] + iG * gG;
      cbuf[p] = c;
      float h = oG * tanhf_(c);
      size_t oidx = (size_t)(n * 1024 + t) * 512 + w * 16 + j;
      // Plain stores: write-through L1 -> winner XCD's L2 (coherence point).
      if (F32) ((float*)outv)[oidx] = h;
      else     ((unsigned short*)outv)[oidx] = f2b(h);
    }
    // Within-XCD release: drain own stores to L2, then all-threads barrier.
    asm volatile("s_waitcnt vmcnt(0)" ::: "memory");
    __syncthreads();   // B2: all h_t stores + gatebuf reads done

    if (t < 1023 && tid == 0) {
      store_flag_l2(bar + w, (unsigned)(t + 1));   // flag[w] = steps completed
    }
  }
  asm volatile("" :: "v"(bu0), "v"(bu1));   // keep burn chains live (rule #17)
}

__global__ __launch_bounds__(256) void lstm_kernel(
    const void* x, const void* h0, const void* Wx, const void* Wh,
    const void* bias, void* out, unsigned* ws) {
  extern __shared__ unsigned char smem[];
  __shared__ unsigned s_role[2];
  unsigned* flags  = ws;          // [0..31]  step flags
  unsigned* cnt    = ws + 32;     // [32..47] per-XCD registration counters
  unsigned* winner = ws + 48;     // 0 = unset, else xcd+1
  unsigned* done   = ws + 49;     // heater stop flag
  // All sync state within first 256 B of ws (memset 256 - proven R4-R6).

  // ---- runtime XCD election (correctness never assumes blockIdx->XCD) ----
  if (threadIdx.x == 0) {
    unsigned xcd;
    asm volatile("s_getreg_b32 %0, hwreg(HW_REG_XCC_ID)" : "=s"(xcd));
    xcd &= 0xFu;
    unsigned rank = atomicAdd(&cnt[xcd], 1u);      // device-scope RMW
    if (rank == 31u) atomicCAS(winner, 0u, xcd + 1u);
    // 256 co-resident WGs / 8 XCDs => some XCD reaches 32 (pigeonhole).
    unsigned wv; int guard = 0;
    do {
      wv = load_dword_dev(winner);
    } while (wv == 0u && ++guard < (1 << 26));
    s_role[0] = (wv == xcd + 1u && rank < 32u) ? 1u : 0u;
    s_role[1] = rank;
  }
  __syncthreads();

  if (s_role[0]) {
    int w = (int)s_role[1];
    if (sniff_is_bf16((const unsigned short*)Wx))
      lstm_body<false>(x, h0, Wx, Wh, bias, out, flags, smem, w);
    else
      lstm_body<true>(x, h0, Wx, Wh, bias, out, flags, smem, w);
    if (w == 0 && threadIdx.x == 0) store_dword_dev(done, 1u);
  } else {
    // R6-verbatim duty-cycled heater on non-winner WGs.
    float a = 1.0f;
    const float bm = 1.0000001f;
    for (int o = 0; o < (1 << 22); ++o) {
#pragma unroll
      for (int i = 0; i < 64; i++) a = __builtin_fmaf(a, bm, 1e-7f);
      __builtin_amdgcn_s_sleep(2);
      if ((o & 63) == 0) {
        if (load_dword_dev(done) != 0u) break;
      }
    }
    asm volatile("" :: "v"(a));   // keep heater work live (rule #17)
  }
}

extern "C" void kernel_launch(void* const* d_in, const int* in_sizes, int n_in,
                              void* d_out, int out_size, void* d_ws, size_t ws_size,
                              hipStream_t stream) {
  const void* x  = d_in[0];
  const void* h0 = d_in[1];
  const void* Wx = d_in[2];
  const void* Wh = d_in[3];
  const void* b  = d_in[4];
  void* out = d_out;
  unsigned* ws = (unsigned*)d_ws;   // poisoned 0xAA each call -> zero it

  hipMemsetAsync(ws, 0, 256, stream);   // flags + cnt + winner + done

  hipFuncSetAttribute((const void*)lstm_kernel,
                      hipFuncAttributeMaxDynamicSharedMemorySize, SMEM_BYTES);

  void* args[] = {(void*)&x, (void*)&h0, (void*)&Wx, (void*)&Wh,
                  (void*)&b, (void*)&out, (void*)&ws};
  hipLaunchCooperativeKernel((const void*)lstm_kernel, dim3(TOTAL_WG), dim3(256),
                             args, SMEM_BYTES, stream);
}

// Round 9
// 24415.898 us; speedup vs baseline: 1.0420x; 1.0306x over previous
//
#include <hip/hip_runtime.h>
#include <hip/hip_bf16.h>

// LSTM: N=32, T=1024, D=H=512, bf16 dataset. Persistent cooperative kernel.
// R13 = R9 (PASSED, 25.2 ms) + precomputed xW (reference-style) — ONE lever.
//   R10/R12 post-mortem: absmax bit-identical (0.8984375) across two
//   different staging geometries + fast completion => global_load_lds writes
//   never landed in LDS (MFMA read deterministic residual LDS bytes). The
//   gll lever is RETIRED (3 rounds). If LDS staging is needed later, use
//   reg-staged ds_write_b128 instead.
// THE R13 LEVER: the serial loop needn't compute x_t@Wx at all (h-independent,
//   exactly what the jax reference hoists). Phase 1: all 256 WGs compute
//   xW = x@Wx fp32 for ALL (t, col-slice) pairs — WG bid handles cols
//   [16*(bid&31),+16) of all 4 gates for t in [128*(bid>>5),+128), using
//   R9's x-part MFMA code verbatim; stores DEVICE-SCOPE write-through
//   (sc0 sc1) so the winner XCD reads coherently (XCD L2s not coherent).
//   Count-up barrier (ws dword 50). Phase 3: R9 serial loop with the x-part
//   DELETED: per step each thread prefetches its 8 xw floats before the
//   flag-wait (hidden latency) and adds them in the epilogue.
//   Removes 32 MFMA + 64 dribbled HBM x-loads (x4 waves) per WG per step
//   from the convoyed critical path. First direct measurement of the
//   x-part's share of the 25 us/step floor.
// ws_size guard: host passes xwbuf=ws+4096 only if ws_size >= 256MB+4KB;
//   else xwbuf=nullptr and the body runs the exact R9 path (guaranteed pass).
// Killed theories: sync mechanism (R4/R5/R6), cross-XCD locality (R6), DPM
// clock parking (R9), global_load_lds staging (R10-R12, mechanism no-op).
// Sync skeleton R9-VERBATIM throughout.

#define NWG 32
#define TOTAL_WG 256
#define LDW 520              // 512 + 8 pad shorts (16B-aligned rows)
#define SMEM_BYTES (2*64*LDW*2 + 4*32*16*4 + 512*4)   // 143360 B
#define XW_BYTES (268435456ULL)   // 32*1024*2048*4 fp32

typedef __attribute__((ext_vector_type(8))) short s16x8;
typedef __attribute__((ext_vector_type(4))) float f32x4;
typedef __attribute__((ext_vector_type(4))) float f4v;

__device__ __forceinline__ float b2f(unsigned short u) {
  unsigned v = ((unsigned)u) << 16;
  return __builtin_bit_cast(float, v);
}
__device__ __forceinline__ unsigned short f2b(float f) {
  unsigned u = __builtin_bit_cast(unsigned, f);
  unsigned r = (u + 0x7fffu + ((u >> 16) & 1u)) >> 16;  // RNE
  return (unsigned short)r;
}
__device__ __forceinline__ float sigmoidf_(float x) {
  return 1.f / (1.f + __expf(-x));
}
__device__ __forceinline__ float tanhf_(float x) {
  float ax = fabsf(x);
  float e = __expf(-2.f * ax);          // in (0,1], no overflow
  float th = (1.f - e) / (1.f + e);
  return copysignf(th, x);
}

// Dependent-FMA chains for wait-phase heat (R9-proven).
__device__ __forceinline__ void burn(float& a, float& b) {
#pragma unroll
  for (int i = 0; i < 64; i++) {
    a = __builtin_fmaf(a, 1.0000002f, 1e-9f);
    b = __builtin_fmaf(b, 0.9999998f, 1e-9f);
  }
}

// ---- XCD-local (L2-scope) sync ops: sc0 bypasses L1 only ----
__device__ __forceinline__ void store_flag_l2(unsigned* p, unsigned v) {
  asm volatile("global_store_dword %0, %1, off sc0"
               :: "v"(p), "v"(v) : "memory");
}
__device__ __forceinline__ unsigned load_flag_l2(const unsigned* p) {
  unsigned r;
  asm volatile("global_load_dword %0, %1, off sc0\n\t"
               "s_waitcnt vmcnt(0)"
               : "=v"(r) : "v"(p) : "memory");
  return r;
}
// ---- device-scope (cross-XCD, MALL) ops ----
__device__ __forceinline__ void store_dword_dev(unsigned* p, unsigned v) {
  asm volatile("global_store_dword %0, %1, off sc0 sc1"
               :: "v"(p), "v"(v) : "memory");
}
__device__ __forceinline__ void store_f32_dev(float* p, float v) {
  unsigned u = __builtin_bit_cast(unsigned, v);
  asm volatile("global_store_dword %0, %1, off sc0 sc1"
               :: "v"(p), "v"(u) : "memory");
}
__device__ __forceinline__ unsigned load_dword_dev(const unsigned* p) {
  unsigned r;
  asm volatile("global_load_dword %0, %1, off sc0 sc1\n\t"
               "s_waitcnt vmcnt(0)"
               : "=v"(r) : "v"(p) : "memory");
  return r;
}

// fp32[8] -> bf16 (fp32 fallback path only)
__device__ __forceinline__ void split8(const float* p, s16x8& hi, s16x8& lo) {
  float tmp[8];
  *(f4v*)&tmp[0] = *(const f4v*)&p[0];
  *(f4v*)&tmp[4] = *(const f4v*)&p[4];
#pragma unroll
  for (int j = 0; j < 8; j++) {
    unsigned short h = f2b(tmp[j]);
    hi[j] = (short)h;
    lo[j] = (short)f2b(tmp[j] - b2f(h));
  }
}
__device__ __forceinline__ s16x8 cvt8(const float* p) {
  float tmp[8];
  *(f4v*)&tmp[0] = *(const f4v*)&p[0];
  *(f4v*)&tmp[4] = *(const f4v*)&p[4];
  s16x8 r;
#pragma unroll
  for (int j = 0; j < 8; j++) r[j] = (short)f2b(tmp[j]);
  return r;
}

// Uniform dtype sniff (one-time): bf16 normals vs fp32-as-halfwords.
__device__ __forceinline__ bool sniff_is_bf16(const unsigned short* wx) {
  int cnt = 0;
  for (int i = 0; i < 512; i++) {
    unsigned e = (wx[i] >> 7) & 0xFF;
    cnt += (e >= 0x60 && e <= 0x9F) ? 1 : 0;
  }
  return cnt >= 440;
}

// ---------------- Phase 1: xW = x @ Wx (bf16, all 256 WGs) ----------------
// WG bid: cols [16*(bid&31),+16) of each gate, t in [128*(bid>>5),+128).
// xwbuf layout: [t][n][2048] fp32; element (t,n,gate,col16w+lm) at
// t*65536 + n*2048 + gate*512 + w2*16 + lm. Device-scope stores.
__device__ __forceinline__ void xw_phase(
    const unsigned short* xb, const unsigned short* Wxv,
    float* __restrict__ xwbuf, unsigned char* smem, int bid, int tid) {
  unsigned short* WxS = (unsigned short*)(smem + 64 * LDW * 2);  // [64][LDW]
  const int w2 = bid & 31;
  const int tc = bid >> 5;
  for (int i = 0; i < 8; i++) {
    int id = tid + i * 256;
    int gate = id & 3;
    int k = id >> 2;
    const unsigned short* px = Wxv + (size_t)k * 2048 + gate * 512 + w2 * 16;
    s16x8 v0 = *(const s16x8*)&px[0];
    s16x8 v1 = *(const s16x8*)&px[8];
#pragma unroll
    for (int j = 0; j < 8; j++) {
      WxS[(gate * 16 + j) * LDW + k]     = (unsigned short)v0[j];
      WxS[(gate * 16 + 8 + j) * LDW + k] = (unsigned short)v1[j];
    }
  }
  __syncthreads();

  const int g = tid >> 6;
  const int lane = tid & 63;
  const int lm = lane & 15;
  const int q = lane >> 4;

  for (int t = tc * 128; t < tc * 128 + 128; t++) {
    f32x4 acc0 = {0.f, 0.f, 0.f, 0.f};
    f32x4 acc1 = {0.f, 0.f, 0.f, 0.f};
    // R9 x-part MFMA, verbatim accumulation order (numerics preserved).
    for (int kc = 0; kc < 16; kc++) {
      int k = kc * 32 + q * 8;
      s16x8 bfrag = *(const s16x8*)&WxS[(g * 16 + lm) * LDW + k];
      s16x8 a0 = *(const s16x8*)&xb[(size_t)(lm * 1024 + t) * 512 + k];
      s16x8 a1 = *(const s16x8*)&xb[(size_t)((16 + lm) * 1024 + t) * 512 + k];
      acc0 = __builtin_amdgcn_mfma_f32_16x16x32_bf16(a0, bfrag, acc0, 0, 0, 0);
      acc1 = __builtin_amdgcn_mfma_f32_16x16x32_bf16(a1, bfrag, acc1, 0, 0, 0);
    }
    // C/D layout: col=lm, row n = q*4+r (acc0) / 16+q*4+r (acc1).
    float* bp = xwbuf + (size_t)t * 65536 + g * 512 + w2 * 16 + lm;
#pragma unroll
    for (int r = 0; r < 4; r++) {
      store_f32_dev(bp + (size_t)(q * 4 + r) * 2048, acc0[r]);
      store_f32_dev(bp + (size_t)(16 + q * 4 + r) * 2048, acc1[r]);
    }
  }
  asm volatile("s_waitcnt vmcnt(0)" ::: "memory");  // drain own dev stores
}

// ---------------- bf16 serial body (R9 skeleton; x-part via xwbuf) --------
__device__ __forceinline__ void lstm_body_bf16(
    const void* xv, const void* h0v, const void* Wxv, const void* Whv,
    const void* biasv, void* outv, unsigned* __restrict__ bar,
    const float* __restrict__ xwbuf, unsigned char* smem, int w) {
  unsigned short* WhS = (unsigned short*)smem;                    // [64][LDW]
  unsigned short* WxS = (unsigned short*)(smem + 64 * LDW * 2);   // [64][LDW]
  float* gatebuf = (float*)(smem + 2 * 64 * LDW * 2);             // [4*32][16]
  float* cbuf = (float*)(smem + 2 * 64 * LDW * 2 + 4 * 32 * 16 * 4); // [512]

  const unsigned short* xb = (const unsigned short*)xv;
  const unsigned short* h0b = (const unsigned short*)h0v;
  unsigned short* outb = (unsigned short*)outv;

  const int tid = threadIdx.x;
  const int g = tid >> 6;          // wave = gate (i,f,o,g)
  const int lane = tid & 63;
  const int lm = lane & 15;
  const int q = lane >> 4;

  float bu0 = 1.0f, bu1 = 1.0f;

  // One-time weight staging (R9-verbatim: both Wx and Wh; Wx unused in xw
  // mode but staging it keeps this path identical to the proven R9 code).
  for (int i = 0; i < 8; i++) {
    int id = tid + i * 256;
    int gate = id & 3;
    int k = id >> 2;
    size_t base = (size_t)k * 2048 + gate * 512 + w * 16;
    const unsigned short* px = (const unsigned short*)Wxv + base;
    const unsigned short* ph = (const unsigned short*)Whv + base;
    s16x8 vx0 = *(const s16x8*)&px[0];
    s16x8 vx1 = *(const s16x8*)&px[8];
    s16x8 vh0 = *(const s16x8*)&ph[0];
    s16x8 vh1 = *(const s16x8*)&ph[8];
#pragma unroll
    for (int j = 0; j < 8; j++) {
      WxS[(gate * 16 + j) * LDW + k]     = (unsigned short)vx0[j];
      WxS[(gate * 16 + 8 + j) * LDW + k] = (unsigned short)vx1[j];
      WhS[(gate * 16 + j) * LDW + k]     = (unsigned short)vh0[j];
      WhS[(gate * 16 + 8 + j) * LDW + k] = (unsigned short)vh1[j];
    }
  }
  cbuf[tid] = 0.f;
  cbuf[tid + 256] = 0.f;

  float bv[2][4];
  for (int pp = 0; pp < 2; pp++) {
    int p = tid + pp * 256;
    int j = p & 15;
    for (int qq = 0; qq < 4; qq++)
      bv[pp][qq] = b2f(((const unsigned short*)biasv)[qq * 512 + w * 16 + j]);
  }
  __syncthreads();

  // xw mode: wait until ALL 256 WGs finished phase 1 (count-up barrier).
  if (xwbuf) {
    if (tid == 0) {
      const unsigned* p1 = bar + 50;
      int guard = 0;
      while (load_dword_dev(p1) < (unsigned)TOTAL_WG) {
        __builtin_amdgcn_s_sleep(2);
        if (++guard > (1 << 24)) break;   // anti-hang; bounded
      }
    }
    __syncthreads();
  }

  for (int t = 0; t < 1024; t++) {
    f32x4 acc0 = {0.f, 0.f, 0.f, 0.f};   // batch rows 0..15
    f32x4 acc1 = {0.f, 0.f, 0.f, 0.f};   // batch rows 16..31
    float xwv[2][4];

    if (xwbuf) {
      // Prefetch this thread's 8 xw floats BEFORE the wait (h-independent;
      // latency hides under the flag poll's vmcnt(0)).
      const float* xt = xwbuf + (size_t)t * 65536 + w * 16;
#pragma unroll
      for (int pp = 0; pp < 2; pp++) {
        int p = tid + pp * 256;
        int n = p >> 4, j = p & 15;
#pragma unroll
        for (int qq = 0; qq < 4; qq++)
          xwv[pp][qq] = xt[(size_t)n * 2048 + qq * 512 + j];
      }
    } else {
      // Fallback: R9-verbatim inline x-part MFMA.
      for (int kc = 0; kc < 16; kc++) {
        int k = kc * 32 + q * 8;
        s16x8 bfrag = *(const s16x8*)&WxS[(g * 16 + lm) * LDW + k];
        s16x8 a0 = *(const s16x8*)&xb[(size_t)(lm * 1024 + t) * 512 + k];
        s16x8 a1 = *(const s16x8*)&xb[(size_t)((16 + lm) * 1024 + t) * 512 + k];
        acc0 = __builtin_amdgcn_mfma_f32_16x16x32_bf16(a0, bfrag, acc0, 0, 0, 0);
        acc1 = __builtin_amdgcn_mfma_f32_16x16x32_bf16(a1, bfrag, acc1, 0, 0, 0);
      }
      xwv[0][0] = xwv[0][1] = xwv[0][2] = xwv[0][3] = 0.f;
      xwv[1][0] = xwv[1][1] = xwv[1][2] = xwv[1][3] = 0.f;
    }

    // ---- wait for h_{t-1} (R9-verbatim: all waves poll + burn) ----
    if (t > 0) {
      const unsigned target = (unsigned)t;
      const unsigned* fp = bar + (lane & 31);
      int guard = 0;
      for (;;) {
        unsigned v = load_flag_l2(fp);
        if (__all(v >= target)) break;
        burn(bu0, bu1);
        if (++guard > (1 << 22)) break;   // anti-hang; never taken co-resident
      }
      asm volatile("buffer_inv" ::: "memory");   // L1-only acquire
    }

    // ---- h-part: R9-verbatim inline loads ----
    {
      const unsigned short* hpb = (t == 0) ? h0b : outb + (size_t)(t - 1) * 512;
      const size_t hstride = (t == 0) ? 512 : (size_t)1024 * 512;
      for (int kc = 0; kc < 16; kc++) {
        int k = kc * 32 + q * 8;
        s16x8 bfrag = *(const s16x8*)&WhS[(g * 16 + lm) * LDW + k];
        s16x8 a0 = *(const s16x8*)&hpb[lm * hstride + k];
        s16x8 a1 = *(const s16x8*)&hpb[(16 + lm) * hstride + k];
        acc0 = __builtin_amdgcn_mfma_f32_16x16x32_bf16(a0, bfrag, acc0, 0, 0, 0);
        acc1 = __builtin_amdgcn_mfma_f32_16x16x32_bf16(a1, bfrag, acc1, 0, 0, 0);
      }
    }

    // C/D layout: col = lane&15 (j), row = q*4 + reg (batch row in 16-block)
    for (int r = 0; r < 4; r++) {
      gatebuf[(g * 32 + q * 4 + r) * 16 + lm] = acc0[r];
      gatebuf[(g * 32 + 16 + q * 4 + r) * 16 + lm] = acc1[r];
    }
    __syncthreads();   // B1

    for (int pp = 0; pp < 2; pp++) {
      int p = tid + pp * 256;
      int n = p >> 4, j = p & 15;
      float ai = gatebuf[(0 * 32 + n) * 16 + j] + xwv[pp][0] + bv[pp][0];
      float af = gatebuf[(1 * 32 + n) * 16 + j] + xwv[pp][1] + bv[pp][1];
      float ao = gatebuf[(2 * 32 + n) * 16 + j] + xwv[pp][2] + bv[pp][2];
      float ag = gatebuf[(3 * 32 + n) * 16 + j] + xwv[pp][3] + bv[pp][3];
      float iG = sigmoidf_(ai);
      float fG = sigmoidf_(af);
      float oG = sigmoidf_(ao);
      float gG = tanhf_(ag);
      float c = fG * cbuf[p] + iG * gG;
      cbuf[p] = c;
      float h = oG * tanhf_(c);
      size_t oidx = (size_t)(n * 1024 + t) * 512 + w * 16 + j;
      outb[oidx] = f2b(h);   // write-through L1 -> winner XCD L2
    }
    asm volatile("s_waitcnt vmcnt(0)" ::: "memory");  // within-XCD release
    __syncthreads();   // B2

    if (t < 1023 && tid == 0) {
      store_flag_l2(bar + w, (unsigned)(t + 1));   // flag[w] = steps completed
    }
  }
  asm volatile("" :: "v"(bu0), "v"(bu1));   // keep burn chains live
}

// ---------------- fp32 fallback (R9-verbatim, correctness only) ------------
__device__ __forceinline__ void lstm_body_f32(
    const void* xv, const void* h0v, const void* Wxv, const void* Whv,
    const void* biasv, void* outv, unsigned* __restrict__ bar,
    unsigned char* smem, int w) {
  unsigned short* WhS = (unsigned short*)smem;
  unsigned short* WxS = (unsigned short*)(smem + 64 * LDW * 2);
  float* gatebuf = (float*)(smem + 2 * 64 * LDW * 2);
  float* cbuf = (float*)(smem + 2 * 64 * LDW * 2 + 4 * 32 * 16 * 4);

  const float* xf = (const float*)xv;
  const float* h0f = (const float*)h0v;

  const int tid = threadIdx.x;
  const int g = tid >> 6;
  const int lane = tid & 63;
  const int lm = lane & 15;
  const int q = lane >> 4;

  float bu0 = 1.0f, bu1 = 1.0f;

  for (int i = 0; i < 8; i++) {
    int id = tid + i * 256;
    int gate = id & 3;
    int k = id >> 2;
    size_t base = (size_t)k * 2048 + gate * 512 + w * 16;
    const float* px = (const float*)Wxv + base;
    const float* ph = (const float*)Whv + base;
#pragma unroll
    for (int seg = 0; seg < 4; seg++) {
      f4v vx = *(const f4v*)(px + seg * 4);
      f4v vh = *(const f4v*)(ph + seg * 4);
#pragma unroll
      for (int j = 0; j < 4; j++) {
        WxS[(gate * 16 + seg * 4 + j) * LDW + k] = f2b(vx[j]);
        WhS[(gate * 16 + seg * 4 + j) * LDW + k] = f2b(vh[j]);
      }
    }
  }
  cbuf[tid] = 0.f;
  cbuf[tid + 256] = 0.f;

  float bv[2][4];
  for (int pp = 0; pp < 2; pp++) {
    int p = tid + pp * 256;
    int j = p & 15;
    for (int qq = 0; qq < 4; qq++)
      bv[pp][qq] = ((const float*)biasv)[qq * 512 + w * 16 + j];
  }
  __syncthreads();

  for (int t = 0; t < 1024; t++) {
    f32x4 acc0 = {0.f, 0.f, 0.f, 0.f};
    f32x4 acc1 = {0.f, 0.f, 0.f, 0.f};

    for (int kc = 0; kc < 16; kc++) {
      int k = kc * 32 + q * 8;
      s16x8 bfrag = *(const s16x8*)&WxS[(g * 16 + lm) * LDW + k];
      s16x8 a0 = cvt8(&xf[(size_t)(lm * 1024 + t) * 512 + k]);
      s16x8 a1 = cvt8(&xf[(size_t)((16 + lm) * 1024 + t) * 512 + k]);
      acc0 = __builtin_amdgcn_mfma_f32_16x16x32_bf16(a0, bfrag, acc0, 0, 0, 0);
      acc1 = __builtin_amdgcn_mfma_f32_16x16x32_bf16(a1, bfrag, acc1, 0, 0, 0);
    }

    if (t > 0) {
      const unsigned target = (unsigned)t;
      const unsigned* fp = bar + (lane & 31);
      int guard = 0;
      for (;;) {
        unsigned v = load_flag_l2(fp);
        if (__all(v >= target)) break;
        burn(bu0, bu1);
        if (++guard > (1 << 22)) break;
      }
      asm volatile("buffer_inv" ::: "memory");
    }

    {
      float* outf = (float*)outv;
      const float* hpf = (t == 0) ? h0f : outf + (size_t)(t - 1) * 512;
      const size_t hstride = (t == 0) ? 512 : (size_t)1024 * 512;
      for (int kc = 0; kc < 16; kc++) {
        int k = kc * 32 + q * 8;
        s16x8 bfrag = *(const s16x8*)&WhS[(g * 16 + lm) * LDW + k];
        s16x8 hi0, lo0, hi1, lo1;
        split8(&hpf[lm * hstride + k], hi0, lo0);
        split8(&hpf[(16 + lm) * hstride + k], hi1, lo1);
        acc0 = __builtin_amdgcn_mfma_f32_16x16x32_bf16(hi0, bfrag, acc0, 0, 0, 0);
        acc0 = __builtin_amdgcn_mfma_f32_16x16x32_bf16(lo0, bfrag, acc0, 0, 0, 0);
        acc1 = __builtin_amdgcn_mfma_f32_16x16x32_bf16(hi1, bfrag, acc1, 0, 0, 0);
        acc1 = __builtin_amdgcn_mfma_f32_16x16x32_bf16(lo1, bfrag, acc1, 0, 0, 0);
      }
    }

    for (int r = 0; r < 4; r++) {
      gatebuf[(g * 32 + q * 4 + r) * 16 + lm] = acc0[r];
      gatebuf[(g * 32 + 16 + q * 4 + r) * 16 + lm] = acc1[r];
    }
    __syncthreads();

    for (int pp = 0; pp < 2; pp++) {
      int p = tid + pp * 256;
      int n = p >> 4, j = p & 15;
      float ai = gatebuf[(0 * 32 + n) * 16 + j] + bv[pp][0];
      float af = gatebuf[(1 * 32 + n) * 16 + j] + bv[pp][1];
      float ao = gatebuf[(2 * 32 + n) * 16 + j] + bv[pp][2];
      float ag = gatebuf[(3 * 32 + n) * 16 + j] + bv[pp][3];
      float iG = sigmoidf_(ai);
      float fG = sigmoidf_(af);
      float oG = sigmoidf_(ao);
      float gG = tanhf_(ag);
      float c = fG * cbuf[p] + iG * gG;
      cbuf[p] = c;
      float h = oG * tanhf_(c);
      size_t oidx = (size_t)(n * 1024 + t) * 512 + w * 16 + j;
      ((float*)outv)[oidx] = h;
    }
    asm volatile("s_waitcnt vmcnt(0)" ::: "memory");
    __syncthreads();

    if (t < 1023 && tid == 0) {
      store_flag_l2(bar + w, (unsigned)(t + 1));
    }
  }
  asm volatile("" :: "v"(bu0), "v"(bu1));
}

__global__ __launch_bounds__(256) void lstm_kernel(
    const void* x, const void* h0, const void* Wx, const void* Wh,
    const void* bias, void* out, unsigned* ws, float* xwbuf) {
  extern __shared__ unsigned char smem[];
  __shared__ unsigned s_role[2];
  unsigned* flags  = ws;          // [0..31]  step flags
  unsigned* cnt    = ws + 32;     // [32..47] per-XCD registration counters
  unsigned* winner = ws + 48;     // 0 = unset, else xcd+1
  unsigned* done   = ws + 49;     // heater stop flag
  unsigned* p1cnt  = ws + 50;     // phase-1 completion counter
  // All sync state within first 256 B of ws (memset 256 - proven R4-R9).

  // ---- runtime XCD election (correctness never assumes blockIdx->XCD) ----
  if (threadIdx.x == 0) {
    unsigned xcd;
    asm volatile("s_getreg_b32 %0, hwreg(HW_REG_XCC_ID)" : "=s"(xcd));
    xcd &= 0xFu;
    unsigned rank = atomicAdd(&cnt[xcd], 1u);      // device-scope RMW
    if (rank == 31u) atomicCAS(winner, 0u, xcd + 1u);
    unsigned wv; int guard = 0;
    do {
      wv = load_dword_dev(winner);
    } while (wv == 0u && ++guard < (1 << 26));
    s_role[0] = (wv == xcd + 1u && rank < 32u) ? 1u : 0u;
    s_role[1] = rank;
  }
  __syncthreads();

  bool isbf = sniff_is_bf16((const unsigned short*)Wx);

  // ---- Phase 1 (xw mode only): every WG computes its xW chunk ----
  if (xwbuf != nullptr) {
    if (isbf)
      xw_phase((const unsigned short*)x, (const unsigned short*)Wx,
               xwbuf, smem, (int)blockIdx.x, (int)threadIdx.x);
    __syncthreads();   // all waves' stores drained (vmcnt in xw_phase)
    if (threadIdx.x == 0) atomicAdd(p1cnt, 1u);   // device-scope count-up
  }

  if (s_role[0]) {
    int w = (int)s_role[1];
    if (isbf)
      lstm_body_bf16(x, h0, Wx, Wh, bias, out, flags,
                     isbf ? xwbuf : nullptr, smem, w);
    else
      lstm_body_f32(x, h0, Wx, Wh, bias, out, flags, smem, w);
    if (w == 0 && threadIdx.x == 0) store_dword_dev(done, 1u);
  } else {
    // R6/R9-verbatim duty-cycled heater on non-winner WGs.
    float a = 1.0f;
    const float bm = 1.0000001f;
    for (int o = 0; o < (1 << 22); ++o) {
#pragma unroll
      for (int i = 0; i < 64; i++) a = __builtin_fmaf(a, bm, 1e-7f);
      __builtin_amdgcn_s_sleep(2);
      if ((o & 63) == 0) {
        if (load_dword_dev(done) != 0u) break;
      }
    }
    asm volatile("" :: "v"(a));
  }
}

extern "C" void kernel_launch(void* const* d_in, const int* in_sizes, int n_in,
                              void* d_out, int out_size, void* d_ws, size_t ws_size,
                              hipStream_t stream) {
  const void* x  = d_in[0];
  const void* h0 = d_in[1];
  const void* Wx = d_in[2];
  const void* Wh = d_in[3];
  const void* b  = d_in[4];
  void* out = d_out;
  unsigned* ws = (unsigned*)d_ws;   // poisoned 0xAA each call -> zero sync area

  hipMemsetAsync(ws, 0, 256, stream);   // flags+cnt+winner+done+p1cnt

  // xw mode only if the workspace can hold the fp32 xW tensor (+4KB header).
  float* xwbuf = nullptr;
  if (ws_size >= XW_BYTES + 4096)
    xwbuf = (float*)((char*)d_ws + 4096);

  hipFuncSetAttribute((const void*)lstm_kernel,
                      hipFuncAttributeMaxDynamicSharedMemorySize, SMEM_BYTES);

  void* args[] = {(void*)&x, (void*)&h0, (void*)&Wx, (void*)&Wh,
                  (void*)&b, (void*)&out, (void*)&ws, (void*)&xwbuf};
  hipLaunchCooperativeKernel((const void*)lstm_kernel, dim3(TOTAL_WG), dim3(256),
                             args, SMEM_BYTES, stream);
}